// Round 18
// baseline (3833.503 us; speedup 1.0000x reference)
//
#include <hip/hip_runtime.h>
#include <hip/hip_bf16.h>

// ---------------------------------------------------------------------------
// H_ACS_Encoder: B=16384, D=1024, A=4096, topk=128, T=0.7
// Outputs (flat): base_emb[B,D], weights[B,A], scores[B,A], euc_raw[B,D], euc_vec[B,D]
//
// ROUND 18: K-panels {512,512}, flat single-accumulator ascending-k chains.
// Rationale: refs compared bf16-rounded (absmax values are adjacent bf16
// codes; out npz ~2B/elem) => bucket-identity inference was weak; surgical
// swaps (R16/R17) break correct rows. Surviving signal: first-panel size
// changes the wrong-row set. {512,512} = AMD AOCL/BLIS KC=512 (likely BLAS
// on EPYC hosts) AND OpenBLAS ZEN if Q=512. BLIS microkernels are flat
// per-element like asm OpenBLAS. Norms = numpy scalar pairwise (validated);
// top-k exact fp32, ties -> lowest index; softmax value-level fp32.
//
// Scratch aliasing (no d_ws):
//   a_norm (A*D f32) -> base_emb region (base_emb written LAST)
//   q      (B*D f32) -> weights region  (dead before weights write)
//   list   (B*256)   -> euc_vec region  (dead before final norm)
// ---------------------------------------------------------------------------

#define B_ROWS 16384
#define D_DIM  1024
#define A_ATOMS 4096
#define K_TOP  128

// K-panel boundary for K=1024, KC=512: single boundary at 512 -> {512,512}
#define PANEL_1 512
#define PANEL_2 99999   // unused

// ---------------- numpy-pairwise row l2-normalize (1 wave/row, 4 rows/blk) --
__global__ __launch_bounds__(256) void rownorm_np_kernel(const float* __restrict__ src,
                                                         float* __restrict__ dst,
                                                         int nrows) {
    const int r = blockIdx.x * 4 + (threadIdx.x >> 6);
    if (r >= nrows) return;
    const int lane = threadIdx.x & 63;
    const int leaf = lane >> 3, j = lane & 7;
    const float* p = src + (size_t)r * D_DIM + leaf * 128 + j;

    float x[16];
    x[0] = p[0];
    float rs = __fmul_rn(x[0], x[0]);
#pragma unroll
    for (int i = 1; i < 16; i++) {
        x[i] = p[i * 8];
        rs = __fadd_rn(rs, __fmul_rn(x[i], x[i]));
    }
    rs = __fadd_rn(rs, __shfl_xor(rs, 1));
    rs = __fadd_rn(rs, __shfl_xor(rs, 2));
    rs = __fadd_rn(rs, __shfl_xor(rs, 4));
    rs = __fadd_rn(rs, __shfl_xor(rs, 8));
    rs = __fadd_rn(rs, __shfl_xor(rs, 16));
    rs = __fadd_rn(rs, __shfl_xor(rs, 32));

    const float nrm = fmaxf(__fsqrt_rn(rs), 1e-12f);
    float* q = dst + (size_t)r * D_DIM + leaf * 128 + j;
#pragma unroll
    for (int i = 0; i < 16; i++) q[i * 8] = __fdiv_rn(x[i], nrm);
}

// ---------------- panel-chained fp32 NT GEMM (flat, {512,512}) -------------
// C[m][n] = (P0 + P1) + bias[n], each panel a flat ascending
// single-accumulator fp32 FMA chain.
#define GT_M 128
#define GT_N 128
#define GT_K 16

__global__ __launch_bounds__(256) void gemm_oblas_f32(const float* __restrict__ A,
                                                      const float* __restrict__ Bm,
                                                      const float* __restrict__ bias,
                                                      float* __restrict__ C,
                                                      int N, int Kd) {
    __shared__ float As[GT_K][GT_M + 4];
    __shared__ float Bs[GT_K][GT_N + 4];
    const int ntiles = N / GT_N;
    const int bn = blockIdx.x % ntiles;
    const int bm = blockIdx.x / ntiles;
    const int m0 = bm * GT_M, n0 = bn * GT_N;
    const int t = threadIdx.x;
    const int tx = t & 15, ty = t >> 4;
    const int lr = t >> 1;
    const int lk = (t & 1) * 8;

    float acc[8][8];   // current panel's flat chain
    float tot[8][8];   // left-fold of completed panels
#pragma unroll
    for (int i = 0; i < 8; i++)
#pragma unroll
        for (int j = 0; j < 8; j++) { acc[i][j] = 0.f; tot[i][j] = 0.f; }

    for (int k0 = 0; k0 < Kd; k0 += GT_K) {
        const float4 a0 = *(const float4*)(A + (size_t)(m0 + lr) * Kd + k0 + lk);
        const float4 a1 = *(const float4*)(A + (size_t)(m0 + lr) * Kd + k0 + lk + 4);
        const float4 b0 = *(const float4*)(Bm + (size_t)(n0 + lr) * Kd + k0 + lk);
        const float4 b1 = *(const float4*)(Bm + (size_t)(n0 + lr) * Kd + k0 + lk + 4);
        __syncthreads();   // protect previous iteration's reads
        As[lk + 0][lr] = a0.x; As[lk + 1][lr] = a0.y; As[lk + 2][lr] = a0.z; As[lk + 3][lr] = a0.w;
        As[lk + 4][lr] = a1.x; As[lk + 5][lr] = a1.y; As[lk + 6][lr] = a1.z; As[lk + 7][lr] = a1.w;
        Bs[lk + 0][lr] = b0.x; Bs[lk + 1][lr] = b0.y; Bs[lk + 2][lr] = b0.z; Bs[lk + 3][lr] = b0.w;
        Bs[lk + 4][lr] = b1.x; Bs[lk + 5][lr] = b1.y; Bs[lk + 6][lr] = b1.z; Bs[lk + 7][lr] = b1.w;
        __syncthreads();
#pragma unroll
        for (int k = 0; k < GT_K; k++) {   // ascending k within panel
            const float4 av0 = *(const float4*)&As[k][ty * 8];
            const float4 av1 = *(const float4*)&As[k][ty * 8 + 4];
            const float4 bv0 = *(const float4*)&Bs[k][tx * 8];
            const float4 bv1 = *(const float4*)&Bs[k][tx * 8 + 4];
            const float af[8] = {av0.x, av0.y, av0.z, av0.w, av1.x, av1.y, av1.z, av1.w};
            const float bf[8] = {bv0.x, bv0.y, bv0.z, bv0.w, bv1.x, bv1.y, bv1.z, bv1.w};
#pragma unroll
            for (int i = 0; i < 8; i++)
#pragma unroll
                for (int j = 0; j < 8; j++)
                    acc[i][j] = __fmaf_rn(af[i], bf[j], acc[i][j]);
        }
        // panel boundary: C += panel  (sequential left-fold fp32 add)
        const int ke = k0 + GT_K;
        if (ke == PANEL_1 || ke == PANEL_2) {
#pragma unroll
            for (int i = 0; i < 8; i++)
#pragma unroll
                for (int j = 0; j < 8; j++) {
                    tot[i][j] = __fadd_rn(tot[i][j], acc[i][j]);
                    acc[i][j] = 0.f;
                }
        }
    }

    float bj[8];
#pragma unroll
    for (int j = 0; j < 8; j++) bj[j] = bias ? bias[n0 + tx * 8 + j] : 0.f;
#pragma unroll
    for (int i = 0; i < 8; i++) {
        const size_t row = (size_t)(m0 + ty * 8 + i);
        float* cp = C + row * (size_t)N + n0 + tx * 8;
        float4 c0, c1;
        c0.x = __fadd_rn(__fadd_rn(tot[i][0], acc[i][0]), bj[0]);
        c0.y = __fadd_rn(__fadd_rn(tot[i][1], acc[i][1]), bj[1]);
        c0.z = __fadd_rn(__fadd_rn(tot[i][2], acc[i][2]), bj[2]);
        c0.w = __fadd_rn(__fadd_rn(tot[i][3], acc[i][3]), bj[3]);
        c1.x = __fadd_rn(__fadd_rn(tot[i][4], acc[i][4]), bj[4]);
        c1.y = __fadd_rn(__fadd_rn(tot[i][5], acc[i][5]), bj[5]);
        c1.z = __fadd_rn(__fadd_rn(tot[i][6], acc[i][6]), bj[6]);
        c1.w = __fadd_rn(__fadd_rn(tot[i][7], acc[i][7]), bj[7]);
        *(float4*)cp = c0;
        *(float4*)(cp + 4) = c1;
    }
}

// ---------------- exact fp32 top-128 (ties -> lowest index) + softmax ------
__device__ __forceinline__ unsigned f2key(float f) {
    unsigned u = __float_as_uint(f);
    return (u & 0x80000000u) ? ~u : (u | 0x80000000u);
}

__global__ __launch_bounds__(256) void topk32_kernel(const float* __restrict__ scores,
                                                     float* __restrict__ weights,
                                                     float* __restrict__ list) {
    __shared__ float s[A_ATOMS];
    __shared__ unsigned hist[256];
    __shared__ int scanb[256];
    __shared__ float fred[8];
    __shared__ unsigned ubc[4];
    __shared__ unsigned char selb[A_ATOMS];

    const int r = blockIdx.x;
    const int t = threadIdx.x;
    const int lane = t & 63, wid = t >> 6;
    const float* srow = scores + (size_t)r * A_ATOMS;

#pragma unroll
    for (int c = 0; c < 4; c++) {
        const int i = c * 1024 + t * 4;
        *(float4*)(s + i) = *(const float4*)(srow + i);
    }
    __syncthreads();

    // 4-pass radix select (8-bit digits, MSB first) for the 128th largest
    unsigned prefix = 0, remaining = K_TOP;
    for (int shift = 24; shift >= 0; shift -= 8) {
        hist[t] = 0u;
        __syncthreads();
        for (int j = 0; j < 16; j++) {
            const unsigned u = f2key(s[t * 16 + j]);
            const bool isc = (shift == 24) || ((u >> (shift + 8)) == (prefix >> (shift + 8)));
            if (isc) atomicAdd(&hist[(u >> shift) & 255u], 1u);
        }
        __syncthreads();
        scanb[t] = (int)hist[t];
        __syncthreads();
        for (int off = 1; off < 256; off <<= 1) {   // suffix scan
            const int add = (t + off < 256) ? scanb[t + off] : 0;
            __syncthreads();
            scanb[t] += add;
            __syncthreads();
        }
        const int sfx = scanb[t];
        const int sfxn = (t < 255) ? scanb[t + 1] : 0;
        if (sfx >= (int)remaining && sfxn < (int)remaining) {
            ubc[0] = prefix | ((unsigned)t << shift);
            ubc[1] = remaining - (unsigned)sfxn;
        }
        __syncthreads();
        prefix = ubc[0];
        remaining = ubc[1];
    }
    const unsigned Tkey = prefix;
    const int need = (int)remaining;   // #equal-to-threshold to include

    // strict winners; equals -> lowest `need` indices (stable, = lax.top_k)
    int myeq = 0;
    for (int j = 0; j < 16; j++) {
        const int i = t * 16 + j;
        const unsigned u = f2key(s[i]);
        selb[i] = (u > Tkey) ? 1 : 0;
        myeq += (u == Tkey) ? 1 : 0;
    }
    scanb[t] = myeq;
    __syncthreads();
    for (int off = 1; off < 256; off <<= 1) {   // inclusive ascending scan
        const int v = scanb[t];
        const int add = (t >= off) ? scanb[t - off] : 0;
        __syncthreads();
        scanb[t] = v + add;
        __syncthreads();
    }
    int epos = scanb[t] - myeq;
    for (int j = 0; j < 16; j++) {
        const int i = t * 16 + j;
        if (f2key(s[i]) == Tkey) { if (epos < need) selb[i] = 1; epos++; }
    }
    __syncthreads();

    // fp32 softmax over selected
    float zmax = -3.4e38f;
    for (int j = 0; j < 16; j++) {
        const int i = t * 16 + j;
        if (selb[i]) zmax = fmaxf(zmax, __fdiv_rn(s[i], 0.7f));
    }
    for (int o = 32; o > 0; o >>= 1) zmax = fmaxf(zmax, __shfl_down(zmax, o, 64));
    if (lane == 0) fred[wid] = zmax;
    __syncthreads();
    if (t == 0) fred[4] = fmaxf(fmaxf(fred[0], fred[1]), fmaxf(fred[2], fred[3]));
    __syncthreads();
    const float zm = fred[4];

    float esum = 0.f;
    int selcnt = 0;
    for (int j = 0; j < 16; j++) {
        const int i = t * 16 + j;
        if (selb[i]) { esum += expf(__fdiv_rn(s[i], 0.7f) - zm); selcnt++; }
    }
    for (int o = 32; o > 0; o >>= 1) esum += __shfl_down(esum, o, 64);
    if (lane == 0) fred[wid] = esum;
    __syncthreads();
    if (t == 0) fred[4] = fred[0] + fred[1] + fred[2] + fred[3];
    __syncthreads();
    const float S = fred[4];

    // dense weights row
    float* wrow = weights + (size_t)r * A_ATOMS;
#pragma unroll
    for (int c = 0; c < 4; c++) {
        const int i = c * 1024 + t * 4;
        float4 w4;
        float wv[4];
#pragma unroll
        for (int j = 0; j < 4; j++) {
            wv[j] = selb[i + j]
                ? __fdiv_rn(expf(__fdiv_rn(s[i + j], 0.7f) - zm), S)
                : 0.f;
        }
        w4.x = wv[0]; w4.y = wv[1]; w4.z = wv[2]; w4.w = wv[3];
        *(float4*)(wrow + i) = w4;
    }

    // compact (idx, w) list in ascending atom-index order (for euc chain)
    __syncthreads();
    scanb[t] = selcnt;
    __syncthreads();
    for (int off = 1; off < 256; off <<= 1) {
        const int v = scanb[t];
        const int add = (t >= off) ? scanb[t - off] : 0;
        __syncthreads();
        scanb[t] = v + add;
        __syncthreads();
    }
    int pos = scanb[t] - selcnt;
    int* li = (int*)(list + (size_t)r * 256);
    float* lw = list + (size_t)r * 256 + 128;
    for (int j = 0; j < 16; j++) {
        const int i = t * 16 + j;
        if (selb[i]) {
            const float w = __fdiv_rn(expf(__fdiv_rn(s[i], 0.7f) - zm), S);
            if (pos < K_TOP) { li[pos] = i; lw[pos] = w; }
            pos++;
        }
    }
}

// ---------------- euc_raw[r] = sum_j w_j * atoms[idx_j] (ascending idx) -----
__global__ __launch_bounds__(256) void euc_gather_kernel(const float* __restrict__ atoms,
                                                         const float* __restrict__ list,
                                                         float* __restrict__ euc) {
    __shared__ int sidx[K_TOP];
    __shared__ float sw[K_TOP];
    const int r = blockIdx.x, t = threadIdx.x;
    if (t < K_TOP) {
        sidx[t] = ((const int*)list)[(size_t)r * 256 + t];
        sw[t] = list[(size_t)r * 256 + 128 + t];
    }
    __syncthreads();
    const float4* A4 = (const float4*)atoms;
    float4 acc = {0.f, 0.f, 0.f, 0.f};
#pragma unroll 4
    for (int j = 0; j < K_TOP; j++) {      // ascending atom index
        const float w = sw[j];
        const float4 a = A4[(size_t)sidx[j] * 256 + t];
        acc.x = __fmaf_rn(w, a.x, acc.x);
        acc.y = __fmaf_rn(w, a.y, acc.y);
        acc.z = __fmaf_rn(w, a.z, acc.z);
        acc.w = __fmaf_rn(w, a.w, acc.w);
    }
    ((float4*)euc)[(size_t)r * 256 + t] = acc;
}

// ---------------------------------------------------------------------------
extern "C" void kernel_launch(void* const* d_in, const int* in_sizes, int n_in,
                              void* d_out, int out_size, void* d_ws, size_t ws_size,
                              hipStream_t stream) {
    const float* base_raw = (const float*)d_in[0];
    const float* W        = (const float*)d_in[1];
    const float* bvec     = (const float*)d_in[2];
    const float* atoms    = (const float*)d_in[3];
    float* out = (float*)d_out;

    const size_t BD = (size_t)B_ROWS * D_DIM;   // 16,777,216
    const size_t BA = (size_t)B_ROWS * A_ATOMS; // 67,108,864
    float* base_emb = out;
    float* weights  = out + BD;
    float* scores   = out + BD + BA;
    float* euc_raw  = out + BD + 2 * BA;
    float* euc_vec  = out + 2 * BD + 2 * BA;

    float* a_norm = base_emb;  // scratch: A*D = 4.2M floats <= BD
    float* q      = weights;   // scratch: B*D floats <= BA
    float* list   = euc_vec;   // scratch: B*256 floats <= BD

    // 1. a_norm = l2norm_np(atoms)
    rownorm_np_kernel<<<A_ATOMS / 4, 256, 0, stream>>>(atoms, a_norm, A_ATOMS);
    // 2. q_raw = base_raw @ W^T + b   (panels {512,512}, flat chains)
    gemm_oblas_f32<<<(B_ROWS / GT_M) * (D_DIM / GT_N), 256, 0, stream>>>(
        base_raw, W, bvec, q, D_DIM, D_DIM);
    // 3. q = l2norm_np(q_raw) in place
    rownorm_np_kernel<<<B_ROWS / 4, 256, 0, stream>>>(q, q, B_ROWS);
    // 4. scores = q @ a_norm^T        (panels {512,512}, flat chains)
    gemm_oblas_f32<<<(B_ROWS / GT_M) * (A_ATOMS / GT_N), 256, 0, stream>>>(
        q, a_norm, nullptr, scores, A_ATOMS, D_DIM);
    // 5. exact fp32 top-128 (stable ties) + fp32 softmax -> weights + list
    topk32_kernel<<<B_ROWS, 256, 0, stream>>>(scores, weights, list);
    // 6. euc_raw = weights @ atoms (sparse gather, ascending index chain)
    euc_gather_kernel<<<B_ROWS, 256, 0, stream>>>(atoms, list, euc_raw);
    // 7. euc_vec = l2norm_np(euc_raw)
    rownorm_np_kernel<<<B_ROWS / 4, 256, 0, stream>>>(euc_raw, euc_vec, B_ROWS);
    // 8. base_emb = l2norm_np(base_raw)  (last: frees a_norm aliasing)
    rownorm_np_kernel<<<B_ROWS / 4, 256, 0, stream>>>(base_raw, base_emb, B_ROWS);
}

// Round 19
// 3816.818 us; speedup vs baseline: 1.0044x; 1.0044x over previous
//
#include <hip/hip_runtime.h>
#include <hip/hip_bf16.h>

// ---------------------------------------------------------------------------
// H_ACS_Encoder: B=16384, D=1024, A=4096, topk=128, T=0.7
// Outputs (flat): base_emb[B,D], weights[B,A], scores[B,A], euc_raw[B,D], euc_vec[B,D]
//
// ROUND 19 (R18 PASSED @ 3833us): np chain = flat ascending fp32 FMA with
// K-panels {512,512} (AOCL/BLIS KC=512). THIS ROUND: pure-perf fix of the
// 4-way LDS bank conflict on Bs inner-loop reads (SQ_LDS_BANK_CONFLICT
// 1.68e8, VALUBusy 47%). Column remap per thread: tx*8+{0..7} ->
// tx*4+{0..3} u 64+tx*4+{0..3}; Bs reads now 4-float-stride (2-way = free).
// Each C element keeps its EXACT per-element chain (flat ascending k within
// {512,512} panels) -> bit-identical scores -> selection unchanged.
//
// Scratch aliasing (no d_ws):
//   a_norm (A*D f32) -> base_emb region (base_emb written LAST)
//   q      (B*D f32) -> weights region  (dead before weights write)
//   list   (B*256)   -> euc_vec region  (dead before final norm)
// ---------------------------------------------------------------------------

#define B_ROWS 16384
#define D_DIM  1024
#define A_ATOMS 4096
#define K_TOP  128

// K-panel boundary for K=1024, KC=512 (validated R18)
#define PANEL_1 512

// ---------------- numpy-pairwise row l2-normalize (1 wave/row, 4 rows/blk) --
__global__ __launch_bounds__(256) void rownorm_np_kernel(const float* __restrict__ src,
                                                         float* __restrict__ dst,
                                                         int nrows) {
    const int r = blockIdx.x * 4 + (threadIdx.x >> 6);
    if (r >= nrows) return;
    const int lane = threadIdx.x & 63;
    const int leaf = lane >> 3, j = lane & 7;
    const float* p = src + (size_t)r * D_DIM + leaf * 128 + j;

    float x[16];
    x[0] = p[0];
    float rs = __fmul_rn(x[0], x[0]);
#pragma unroll
    for (int i = 1; i < 16; i++) {
        x[i] = p[i * 8];
        rs = __fadd_rn(rs, __fmul_rn(x[i], x[i]));
    }
    rs = __fadd_rn(rs, __shfl_xor(rs, 1));
    rs = __fadd_rn(rs, __shfl_xor(rs, 2));
    rs = __fadd_rn(rs, __shfl_xor(rs, 4));
    rs = __fadd_rn(rs, __shfl_xor(rs, 8));
    rs = __fadd_rn(rs, __shfl_xor(rs, 16));
    rs = __fadd_rn(rs, __shfl_xor(rs, 32));

    const float nrm = fmaxf(__fsqrt_rn(rs), 1e-12f);
    float* q = dst + (size_t)r * D_DIM + leaf * 128 + j;
#pragma unroll
    for (int i = 0; i < 16; i++) q[i * 8] = __fdiv_rn(x[i], nrm);
}

// ---------------- panel-chained fp32 NT GEMM (flat, {512,512}) -------------
// C[m][n] = (P0 + P1) + bias[n]; per-element flat ascending FMA chain.
// Thread (tx,ty) computes rows ty*8+{0..7}, cols tx*4+{0..3} and 64+tx*4+{0..3}.
#define GT_M 128
#define GT_N 128
#define GT_K 16

__global__ __launch_bounds__(256) void gemm_oblas_f32(const float* __restrict__ A,
                                                      const float* __restrict__ Bm,
                                                      const float* __restrict__ bias,
                                                      float* __restrict__ C,
                                                      int N, int Kd) {
    __shared__ float As[GT_K][GT_M + 4];
    __shared__ float Bs[GT_K][GT_N + 4];
    const int ntiles = N / GT_N;
    const int bn = blockIdx.x % ntiles;
    const int bm = blockIdx.x / ntiles;
    const int m0 = bm * GT_M, n0 = bn * GT_N;
    const int t = threadIdx.x;
    const int tx = t & 15, ty = t >> 4;
    const int lr = t >> 1;
    const int lk = (t & 1) * 8;

    float acc[8][8];   // current panel's flat chain  [row][colgrp*4+j]
    float tot[8][8];   // left-fold of completed panels
#pragma unroll
    for (int i = 0; i < 8; i++)
#pragma unroll
        for (int j = 0; j < 8; j++) { acc[i][j] = 0.f; tot[i][j] = 0.f; }

    for (int k0 = 0; k0 < Kd; k0 += GT_K) {
        const float4 a0 = *(const float4*)(A + (size_t)(m0 + lr) * Kd + k0 + lk);
        const float4 a1 = *(const float4*)(A + (size_t)(m0 + lr) * Kd + k0 + lk + 4);
        const float4 b0 = *(const float4*)(Bm + (size_t)(n0 + lr) * Kd + k0 + lk);
        const float4 b1 = *(const float4*)(Bm + (size_t)(n0 + lr) * Kd + k0 + lk + 4);
        __syncthreads();   // protect previous iteration's reads
        As[lk + 0][lr] = a0.x; As[lk + 1][lr] = a0.y; As[lk + 2][lr] = a0.z; As[lk + 3][lr] = a0.w;
        As[lk + 4][lr] = a1.x; As[lk + 5][lr] = a1.y; As[lk + 6][lr] = a1.z; As[lk + 7][lr] = a1.w;
        Bs[lk + 0][lr] = b0.x; Bs[lk + 1][lr] = b0.y; Bs[lk + 2][lr] = b0.z; Bs[lk + 3][lr] = b0.w;
        Bs[lk + 4][lr] = b1.x; Bs[lk + 5][lr] = b1.y; Bs[lk + 6][lr] = b1.z; Bs[lk + 7][lr] = b1.w;
        __syncthreads();
#pragma unroll
        for (int k = 0; k < GT_K; k++) {   // ascending k within panel
            const float4 av0 = *(const float4*)&As[k][ty * 8];
            const float4 av1 = *(const float4*)&As[k][ty * 8 + 4];
            const float4 bv0 = *(const float4*)&Bs[k][tx * 4];        // 2-way (free)
            const float4 bv1 = *(const float4*)&Bs[k][64 + tx * 4];   // 2-way (free)
            const float af[8] = {av0.x, av0.y, av0.z, av0.w, av1.x, av1.y, av1.z, av1.w};
            const float bf[8] = {bv0.x, bv0.y, bv0.z, bv0.w, bv1.x, bv1.y, bv1.z, bv1.w};
#pragma unroll
            for (int i = 0; i < 8; i++)
#pragma unroll
                for (int j = 0; j < 8; j++)
                    acc[i][j] = __fmaf_rn(af[i], bf[j], acc[i][j]);
        }
        // panel boundary: C += panel  (sequential left-fold fp32 add)
        if (k0 + GT_K == PANEL_1) {
#pragma unroll
            for (int i = 0; i < 8; i++)
#pragma unroll
                for (int j = 0; j < 8; j++) {
                    tot[i][j] = __fadd_rn(tot[i][j], acc[i][j]);
                    acc[i][j] = 0.f;
                }
        }
    }

    float bj[8];
#pragma unroll
    for (int j = 0; j < 4; j++) {
        bj[j]     = bias ? bias[n0 + tx * 4 + j]      : 0.f;
        bj[4 + j] = bias ? bias[n0 + 64 + tx * 4 + j] : 0.f;
    }
#pragma unroll
    for (int i = 0; i < 8; i++) {
        const size_t row = (size_t)(m0 + ty * 8 + i);
        float4 c0, c1;
        c0.x = __fadd_rn(__fadd_rn(tot[i][0], acc[i][0]), bj[0]);
        c0.y = __fadd_rn(__fadd_rn(tot[i][1], acc[i][1]), bj[1]);
        c0.z = __fadd_rn(__fadd_rn(tot[i][2], acc[i][2]), bj[2]);
        c0.w = __fadd_rn(__fadd_rn(tot[i][3], acc[i][3]), bj[3]);
        c1.x = __fadd_rn(__fadd_rn(tot[i][4], acc[i][4]), bj[4]);
        c1.y = __fadd_rn(__fadd_rn(tot[i][5], acc[i][5]), bj[5]);
        c1.z = __fadd_rn(__fadd_rn(tot[i][6], acc[i][6]), bj[6]);
        c1.w = __fadd_rn(__fadd_rn(tot[i][7], acc[i][7]), bj[7]);
        *(float4*)(C + row * (size_t)N + n0 + tx * 4) = c0;
        *(float4*)(C + row * (size_t)N + n0 + 64 + tx * 4) = c1;
    }
}

// ---------------- exact fp32 top-128 (ties -> lowest index) + softmax ------
__device__ __forceinline__ unsigned f2key(float f) {
    unsigned u = __float_as_uint(f);
    return (u & 0x80000000u) ? ~u : (u | 0x80000000u);
}

__global__ __launch_bounds__(256) void topk32_kernel(const float* __restrict__ scores,
                                                     float* __restrict__ weights,
                                                     float* __restrict__ list) {
    __shared__ float s[A_ATOMS];
    __shared__ unsigned hist[256];
    __shared__ int scanb[256];
    __shared__ float fred[8];
    __shared__ unsigned ubc[4];
    __shared__ unsigned char selb[A_ATOMS];

    const int r = blockIdx.x;
    const int t = threadIdx.x;
    const int lane = t & 63, wid = t >> 6;
    const float* srow = scores + (size_t)r * A_ATOMS;

#pragma unroll
    for (int c = 0; c < 4; c++) {
        const int i = c * 1024 + t * 4;
        *(float4*)(s + i) = *(const float4*)(srow + i);
    }
    __syncthreads();

    // 4-pass radix select (8-bit digits, MSB first) for the 128th largest
    unsigned prefix = 0, remaining = K_TOP;
    for (int shift = 24; shift >= 0; shift -= 8) {
        hist[t] = 0u;
        __syncthreads();
        for (int j = 0; j < 16; j++) {
            const unsigned u = f2key(s[t * 16 + j]);
            const bool isc = (shift == 24) || ((u >> (shift + 8)) == (prefix >> (shift + 8)));
            if (isc) atomicAdd(&hist[(u >> shift) & 255u], 1u);
        }
        __syncthreads();
        scanb[t] = (int)hist[t];
        __syncthreads();
        for (int off = 1; off < 256; off <<= 1) {   // suffix scan
            const int add = (t + off < 256) ? scanb[t + off] : 0;
            __syncthreads();
            scanb[t] += add;
            __syncthreads();
        }
        const int sfx = scanb[t];
        const int sfxn = (t < 255) ? scanb[t + 1] : 0;
        if (sfx >= (int)remaining && sfxn < (int)remaining) {
            ubc[0] = prefix | ((unsigned)t << shift);
            ubc[1] = remaining - (unsigned)sfxn;
        }
        __syncthreads();
        prefix = ubc[0];
        remaining = ubc[1];
    }
    const unsigned Tkey = prefix;
    const int need = (int)remaining;   // #equal-to-threshold to include

    // strict winners; equals -> lowest `need` indices (stable)
    int myeq = 0;
    for (int j = 0; j < 16; j++) {
        const int i = t * 16 + j;
        const unsigned u = f2key(s[i]);
        selb[i] = (u > Tkey) ? 1 : 0;
        myeq += (u == Tkey) ? 1 : 0;
    }
    scanb[t] = myeq;
    __syncthreads();
    for (int off = 1; off < 256; off <<= 1) {   // inclusive ascending scan
        const int v = scanb[t];
        const int add = (t >= off) ? scanb[t - off] : 0;
        __syncthreads();
        scanb[t] = v + add;
        __syncthreads();
    }
    int epos = scanb[t] - myeq;
    for (int j = 0; j < 16; j++) {
        const int i = t * 16 + j;
        if (f2key(s[i]) == Tkey) { if (epos < need) selb[i] = 1; epos++; }
    }
    __syncthreads();

    // fp32 softmax over selected
    float zmax = -3.4e38f;
    for (int j = 0; j < 16; j++) {
        const int i = t * 16 + j;
        if (selb[i]) zmax = fmaxf(zmax, __fdiv_rn(s[i], 0.7f));
    }
    for (int o = 32; o > 0; o >>= 1) zmax = fmaxf(zmax, __shfl_down(zmax, o, 64));
    if (lane == 0) fred[wid] = zmax;
    __syncthreads();
    if (t == 0) fred[4] = fmaxf(fmaxf(fred[0], fred[1]), fmaxf(fred[2], fred[3]));
    __syncthreads();
    const float zm = fred[4];

    float esum = 0.f;
    int selcnt = 0;
    for (int j = 0; j < 16; j++) {
        const int i = t * 16 + j;
        if (selb[i]) { esum += expf(__fdiv_rn(s[i], 0.7f) - zm); selcnt++; }
    }
    for (int o = 32; o > 0; o >>= 1) esum += __shfl_down(esum, o, 64);
    if (lane == 0) fred[wid] = esum;
    __syncthreads();
    if (t == 0) fred[4] = fred[0] + fred[1] + fred[2] + fred[3];
    __syncthreads();
    const float S = fred[4];

    // dense weights row
    float* wrow = weights + (size_t)r * A_ATOMS;
#pragma unroll
    for (int c = 0; c < 4; c++) {
        const int i = c * 1024 + t * 4;
        float4 w4;
        float wv[4];
#pragma unroll
        for (int j = 0; j < 4; j++) {
            wv[j] = selb[i + j]
                ? __fdiv_rn(expf(__fdiv_rn(s[i + j], 0.7f) - zm), S)
                : 0.f;
        }
        w4.x = wv[0]; w4.y = wv[1]; w4.z = wv[2]; w4.w = wv[3];
        *(float4*)(wrow + i) = w4;
    }

    // compact (idx, w) list in ascending atom-index order (for euc chain)
    __syncthreads();
    scanb[t] = selcnt;
    __syncthreads();
    for (int off = 1; off < 256; off <<= 1) {
        const int v = scanb[t];
        const int add = (t >= off) ? scanb[t - off] : 0;
        __syncthreads();
        scanb[t] = v + add;
        __syncthreads();
    }
    int pos = scanb[t] - selcnt;
    int* li = (int*)(list + (size_t)r * 256);
    float* lw = list + (size_t)r * 256 + 128;
    for (int j = 0; j < 16; j++) {
        const int i = t * 16 + j;
        if (selb[i]) {
            const float w = __fdiv_rn(expf(__fdiv_rn(s[i], 0.7f) - zm), S);
            if (pos < K_TOP) { li[pos] = i; lw[pos] = w; }
            pos++;
        }
    }
}

// ---------------- euc_raw[r] = sum_j w_j * atoms[idx_j] (ascending idx) -----
__global__ __launch_bounds__(256) void euc_gather_kernel(const float* __restrict__ atoms,
                                                         const float* __restrict__ list,
                                                         float* __restrict__ euc) {
    __shared__ int sidx[K_TOP];
    __shared__ float sw[K_TOP];
    const int r = blockIdx.x, t = threadIdx.x;
    if (t < K_TOP) {
        sidx[t] = ((const int*)list)[(size_t)r * 256 + t];
        sw[t] = list[(size_t)r * 256 + 128 + t];
    }
    __syncthreads();
    const float4* A4 = (const float4*)atoms;
    float4 acc = {0.f, 0.f, 0.f, 0.f};
#pragma unroll 4
    for (int j = 0; j < K_TOP; j++) {      // ascending atom index
        const float w = sw[j];
        const float4 a = A4[(size_t)sidx[j] * 256 + t];
        acc.x = __fmaf_rn(w, a.x, acc.x);
        acc.y = __fmaf_rn(w, a.y, acc.y);
        acc.z = __fmaf_rn(w, a.z, acc.z);
        acc.w = __fmaf_rn(w, a.w, acc.w);
    }
    ((float4*)euc)[(size_t)r * 256 + t] = acc;
}

// ---------------------------------------------------------------------------
extern "C" void kernel_launch(void* const* d_in, const int* in_sizes, int n_in,
                              void* d_out, int out_size, void* d_ws, size_t ws_size,
                              hipStream_t stream) {
    const float* base_raw = (const float*)d_in[0];
    const float* W        = (const float*)d_in[1];
    const float* bvec     = (const float*)d_in[2];
    const float* atoms    = (const float*)d_in[3];
    float* out = (float*)d_out;

    const size_t BD = (size_t)B_ROWS * D_DIM;   // 16,777,216
    const size_t BA = (size_t)B_ROWS * A_ATOMS; // 67,108,864
    float* base_emb = out;
    float* weights  = out + BD;
    float* scores   = out + BD + BA;
    float* euc_raw  = out + BD + 2 * BA;
    float* euc_vec  = out + 2 * BD + 2 * BA;

    float* a_norm = base_emb;  // scratch: A*D = 4.2M floats <= BD
    float* q      = weights;   // scratch: B*D floats <= BA
    float* list   = euc_vec;   // scratch: B*256 floats <= BD

    // 1. a_norm = l2norm_np(atoms)
    rownorm_np_kernel<<<A_ATOMS / 4, 256, 0, stream>>>(atoms, a_norm, A_ATOMS);
    // 2. q_raw = base_raw @ W^T + b   (panels {512,512}, flat chains)
    gemm_oblas_f32<<<(B_ROWS / GT_M) * (D_DIM / GT_N), 256, 0, stream>>>(
        base_raw, W, bvec, q, D_DIM, D_DIM);
    // 3. q = l2norm_np(q_raw) in place
    rownorm_np_kernel<<<B_ROWS / 4, 256, 0, stream>>>(q, q, B_ROWS);
    // 4. scores = q @ a_norm^T        (panels {512,512}, flat chains)
    gemm_oblas_f32<<<(B_ROWS / GT_M) * (A_ATOMS / GT_N), 256, 0, stream>>>(
        q, a_norm, nullptr, scores, A_ATOMS, D_DIM);
    // 5. exact fp32 top-128 (stable ties) + fp32 softmax -> weights + list
    topk32_kernel<<<B_ROWS, 256, 0, stream>>>(scores, weights, list);
    // 6. euc_raw = weights @ atoms (sparse gather, ascending index chain)
    euc_gather_kernel<<<B_ROWS, 256, 0, stream>>>(atoms, list, euc_raw);
    // 7. euc_vec = l2norm_np(euc_raw)
    rownorm_np_kernel<<<B_ROWS / 4, 256, 0, stream>>>(euc_raw, euc_vec, B_ROWS);
    // 8. base_emb = l2norm_np(base_raw)  (last: frees a_norm aliasing)
    rownorm_np_kernel<<<B_ROWS / 4, 256, 0, stream>>>(base_raw, base_emb, B_ROWS);
}